// Round 4
// baseline (1067.710 us; speedup 1.0000x reference)
//
#include <hip/hip_runtime.h>

// HybridSatelliteNormalizer: per-(B,C) channel percentile normalization.
// x: (16,3,1024,1024) fp32. 48 channels x 1,048,576 px each.
// Exact k-th-value via 2-level histogram (1024 coarse x 1024 fine), then apply.
//
// Round-3 post-mortem: per-pass throughput is ~1.5-1.9 TB/s regardless of
// occupancy (3 blocks/CU fused == 8 blocks/CU split) -> not occupancy-bound.
// This revision: ONE persistent kernel (regular launch, software grid barrier,
// grid=1536=6/CU guaranteed resident under __launch_bounds__(256,8): VGPR<=64,
// LDS 9.2KB -> capacity 8/CU) so our code finally appears in the rocprof
// top-5 with real counters, plus a ping-pong register pipeline in all three
// streaming loops so ~4 loads stay in flight during compute (the old
// load-8/drain/compute-32 rhythm had zero loads outstanding during compute).
// Cross-XCD coherence: hist/sub written ONLY via device-scope atomics; read
// after barriers ONLY via agent-scope atomic loads; barrier itself uses
// __hip_atomic_* agent-scope ops.

#define HW (1024 * 1024)
#define NCH 48
#define BPC 32
#define NBLK (NCH * BPC)                    // 1536 blocks = 6 per CU
#define F4_PER_BLOCK (HW / BPC / 4)         // 8192 float4 per block
#define F4_PER_THREAD (F4_PER_BLOCK / 256)  // 32 per thread
#define U 4                                 // float4 per half-batch (ping-pong)

typedef float f32x4 __attribute__((ext_vector_type(4)));

__device__ __forceinline__ unsigned agload(const unsigned* p) {
    return __hip_atomic_load(p, __ATOMIC_RELAXED, __HIP_MEMORY_SCOPE_AGENT);
}

// Software grid barrier: monotonic per-epoch counter in workspace (zeroed by
// the memset). One arrive per block; thread 0 spins on an agent-scope load.
__device__ __forceinline__ void grid_barrier(unsigned* bar) {
    __syncthreads();
    if (threadIdx.x == 0) {
        __threadfence();  // release: make this block's writes visible
        __hip_atomic_fetch_add(bar, 1u, __ATOMIC_ACQ_REL, __HIP_MEMORY_SCOPE_AGENT);
        while (__hip_atomic_load(bar, __ATOMIC_ACQUIRE, __HIP_MEMORY_SCOPE_AGENT) <
               (unsigned)NBLK) {
            __builtin_amdgcn_s_sleep(8);
        }
        __threadfence();  // acquire: see other blocks' writes
    }
    __syncthreads();
}

// Inclusive prefix-scan of g[0..1023] into LDS s[0..1023]; part = LDS[256]
// temp. Reads g via agent-scope atomic loads (coherent vs other XCDs'
// atomicAdds). 256 threads; ends with a barrier.
__device__ __forceinline__ void scan1024_ag(const unsigned* __restrict__ g,
                                            unsigned* __restrict__ s,
                                            unsigned* __restrict__ part) {
    const int t = threadIdx.x;
    const unsigned g0 = agload(&g[4 * t + 0]);
    const unsigned g1 = agload(&g[4 * t + 1]);
    const unsigned g2 = agload(&g[4 * t + 2]);
    const unsigned g3 = agload(&g[4 * t + 3]);
    const unsigned p01 = g0 + g1;
    const unsigned p012 = p01 + g2;
    const unsigned sum = p012 + g3;
    part[t] = sum;
    __syncthreads();
    for (int off = 1; off < 256; off <<= 1) {
        unsigned q = (t >= off) ? part[t - off] : 0u;
        __syncthreads();
        part[t] += q;
        __syncthreads();
    }
    const unsigned excl = (t == 0) ? 0u : part[t - 1];
    s[4 * t + 0] = excl + g0;
    s[4 * t + 1] = excl + p01;
    s[4 * t + 2] = excl + p012;
    s[4 * t + 3] = excl + sum;
    __syncthreads();
}

// Ping-pong stream over this block's chunk: loads of half-batch k+1 are
// issued BEFORE processing half-batch k, keeping U loads in flight during
// compute. Fully static structure (no runtime-indexed register arrays).
template <class Fn>
__device__ __forceinline__ void stream_chunk(const f32x4* __restrict__ xv,
                                             const int t, Fn proc) {
    f32x4 A_[U], B_[U];
#define LDB(D, bb)                                                     \
    {                                                                  \
        _Pragma("unroll") for (int u = 0; u < U; ++u) D[u] =           \
            xv[((bb) * U + u) * 256 + t];                              \
    }
    LDB(A_, 0)
    LDB(B_, 1) proc(A_, 0);
    LDB(A_, 2) proc(B_, 1);
    LDB(B_, 3) proc(A_, 2);
    LDB(A_, 4) proc(B_, 3);
    LDB(B_, 5) proc(A_, 4);
    LDB(A_, 6) proc(B_, 5);
    LDB(B_, 7) proc(A_, 6);
    proc(B_, 7);
#undef LDB
}

__device__ __forceinline__ float apply_one(float xx, float mn, float isc,
                                           float mean, float istd) {
    float y = (xx - mn) * isc;
    y = fminf(fmaxf(y, 0.0f), 1.0f);
    // y^(1/2.2) via hw log2/exp2; exactly 0 at y==0 like the reference
    const float g = 0.45454547f;
    float p = (y > 0.0f) ? exp2f(g * log2f(y)) : 0.0f;
    return (p - mean) * istd;
}

__global__ __launch_bounds__(256, 8) void k_persist(
        const float* __restrict__ x, float* __restrict__ out,
        unsigned* __restrict__ hist, unsigned* __restrict__ sub2,
        unsigned* __restrict__ sub98, unsigned* __restrict__ bars) {
    __shared__ unsigned lh[1024];
    __shared__ unsigned s[1024];
    __shared__ unsigned part[256];
    __shared__ int sf2, sf98;

    const int t = threadIdx.x;
    const int ch = (int)blockIdx.x / BPC;
    const long long base = (long long)blockIdx.x * F4_PER_BLOCK;
    const f32x4* __restrict__ xv = (const f32x4*)x + base;
    unsigned* __restrict__ gh = hist + ch * 1024;

    // ---------------- Phase A: coarse 1024-bin histogram ----------------
    for (int i = t; i < 1024; i += 256) lh[i] = 0u;
    __syncthreads();
    stream_chunk(xv, t, [&](const f32x4 (&v)[U], int) {
#pragma unroll
        for (int u = 0; u < U; ++u) {
#pragma unroll
            for (int k = 0; k < 4; ++k) {
                const float f = v[u][k];
                if (f > 1e-4f) {
                    int j = (int)(f * 1048576.0f);
                    j = min(j, 1048575);
                    atomicAdd(&lh[j >> 10], 1u);
                }
            }
        }
    });
    __syncthreads();
    for (int i = t; i < 1024; i += 256) {
        const unsigned c = lh[i];
        if (c) atomicAdd(&gh[i], c);  // device-scope by default
    }

    grid_barrier(bars + 0);

    // ---------------- Phase B: coarse select + fine sub-histograms ------
    // Every block computes the (identical) selection from the same hist;
    // block-uniform values live in registers across the next barrier.
    scan1024_ag(gh, s, part);
    const int n = (int)s[1023];
    int b2 = -2, r2 = 0, b98 = -2, r98 = 0;
    if (n > 0) {
        // reference: k = min(p*n//100 + 1, n); idx = k-1 -> min(p*n/100, n-1)
        const int i2 = min((2 * n) / 100, n - 1);
        const int i98 = min((98 * n) / 100, n - 1);  // 98n < 2^31 fits int32
        // each thread scans its 4 bins; winners publish to LDS, then all read
        __shared__ int sb2, sr2, sb98, sr98;
#pragma unroll
        for (int q = 0; q < 4; ++q) {
            const int b = 4 * t + q;
            const unsigned excl = (b == 0) ? 0u : s[b - 1];
            const unsigned incl = s[b];
            if (excl <= (unsigned)i2 && (unsigned)i2 < incl) { sb2 = b; sr2 = i2 - (int)excl; }
            if (excl <= (unsigned)i98 && (unsigned)i98 < incl) { sb98 = b; sr98 = i98 - (int)excl; }
        }
        __syncthreads();
        b2 = sb2; r2 = sr2; b98 = sb98; r98 = sr98;

        unsigned* __restrict__ g2 = sub2 + ch * 1024;
        unsigned* __restrict__ g98 = sub98 + ch * 1024;
        stream_chunk(xv, t, [&](const f32x4 (&v)[U], int) {
#pragma unroll
            for (int u = 0; u < U; ++u) {
#pragma unroll
                for (int k = 0; k < 4; ++k) {
                    const float f = v[u][k];
                    if (f > 1e-4f) {
                        int j = (int)(f * 1048576.0f);  // identical expr to A
                        j = min(j, 1048575);
                        const int cb = j >> 10, fb = j & 1023;
                        if (cb == b2) atomicAdd(&g2[fb], 1u);
                        if (cb == b98) atomicAdd(&g98[fb], 1u);
                    }
                }
            }
        });
    }

    grid_barrier(bars + 1);

    // ---------------- Phase C: fine select + apply ----------------------
    if (t == 0) { sf2 = 0; sf98 = 0; }  // ordered by scan's internal barriers
    if (n > 0) {
        scan1024_ag(sub2 + ch * 1024, s, part);
#pragma unroll
        for (int q = 0; q < 4; ++q) {
            const int b = 4 * t + q;
            const unsigned excl = (b == 0) ? 0u : s[b - 1];
            const unsigned incl = s[b];
            if (excl <= (unsigned)r2 && (unsigned)r2 < incl) sf2 = b;
        }
        scan1024_ag(sub98 + ch * 1024, s, part);  // barrier discipline protects s
#pragma unroll
        for (int q = 0; q < 4; ++q) {
            const int b = 4 * t + q;
            const unsigned excl = (b == 0) ? 0u : s[b - 1];
            const unsigned incl = s[b];
            if (excl <= (unsigned)r98 && (unsigned)r98 < incl) sf98 = b;
        }
    }
    __syncthreads();

    const bool use = n > 100;
    float mn, isc;
    if (use) {
        const float v2 = ((float)(b2 * 1024 + sf2) + 0.5f) * (1.0f / 1048576.0f);
        const float v98 = ((float)(b98 * 1024 + sf98) + 0.5f) * (1.0f / 1048576.0f);
        mn = v2;
        isc = 1.0f / fmaxf(v98 - v2, 1e-6f);
    } else {
        mn = 0.0f;
        isc = 1.0f;  // 1/max(1-0, 1e-6)
    }
    const int c3 = ch % 3;
    const float mean = (c3 == 0) ? 0.485f : (c3 == 1) ? 0.456f : 0.406f;
    const float istd = (c3 == 0) ? (1.0f / 0.229f)
                      : (c3 == 1) ? (1.0f / 0.224f) : (1.0f / 0.225f);

    f32x4* __restrict__ ov = (f32x4*)out + base;
    stream_chunk(xv, t, [&](const f32x4 (&v)[U], int bb) {
#pragma unroll
        for (int u = 0; u < U; ++u) {
            f32x4 r;
            r.x = apply_one(v[u].x, mn, isc, mean, istd);
            r.y = apply_one(v[u].y, mn, isc, mean, istd);
            r.z = apply_one(v[u].z, mn, isc, mean, istd);
            r.w = apply_one(v[u].w, mn, isc, mean, istd);
            __builtin_nontemporal_store(r, &ov[(bb * U + u) * 256 + t]);
        }
    });
}

extern "C" void kernel_launch(void* const* d_in, const int* in_sizes, int n_in,
                              void* d_out, int out_size, void* d_ws, size_t ws_size,
                              hipStream_t stream) {
    const float* x = (const float*)d_in[0];
    float* out = (float*)d_out;

    // workspace: hist 48*1024 u32 | sub2 48*1024 u32 | sub98 48*1024 u32
    //          | bars 2 u32 (+pad)
    unsigned* hist = (unsigned*)d_ws;
    unsigned* sub2 = hist + NCH * 1024;
    unsigned* sub98 = sub2 + NCH * 1024;
    unsigned* bars = sub98 + NCH * 1024;
    const size_t ws_zero = (size_t)(3 * NCH * 1024 + 16) * 4;

    hipMemsetAsync(d_ws, 0, ws_zero, stream);
    k_persist<<<NBLK, 256, 0, stream>>>(x, out, hist, sub2, sub98, bars);
}

// Round 5
// 418.249 us; speedup vs baseline: 2.5528x; 2.5528x over previous
//
#include <hip/hip_runtime.h>

// HybridSatelliteNormalizer: per-(B,C) channel percentile normalization.
// x: (16,3,1024,1024) fp32. 48 channels x 1,048,576 px each.
// Exact k-th-value via 2-level histogram (1024 coarse x 1024 fine), then apply.
//
// Round-4 post-mortem: occupancy 35% vs 71% -> identical slowness; VALU/LDS/
// HBM all <15% busy. Everything points at the address-stream structure:
// block-chunked mapping = ~1500 concurrent sequential DRAM streams (row-buffer
// thrash), vs the harness fill's grid-stride walk at 6.5 TB/s. This revision
// keeps the proven 4-dispatch chassis (round 3) and changes ONLY the mapping:
// within each channel, its 32 blocks walk the channel's 4MB together
// (block-interleaved), so each iteration touches one contiguous 128KB window
// per channel -> ~48 sequential streams device-wide instead of ~1500.

#define HW (1024 * 1024)
#define NCH 48
#define BPC 32
#define GRID_STREAM (NCH * BPC)          // 1536 blocks
#define F4_PER_CH (HW / 4)               // 262144 float4 per channel
#define STRIDE_F4 (BPC * 256)            // 8192 float4 = 128KB per channel-step
#define NIT (F4_PER_CH / STRIDE_F4)      // 32 iterations
#define UNROLL 8

typedef float f32x4 __attribute__((ext_vector_type(4)));

// Inclusive prefix-scan of g[0..1023] into LDS s[0..1023]; part = LDS[256]
// temp. 256 threads; ends with a barrier. Safe to call repeatedly with the
// same LDS buffers: callers' reads of s from a prior call all happen before
// this call's internal barriers, and s is rewritten only after those.
__device__ __forceinline__ void scan1024(const unsigned* __restrict__ g,
                                         unsigned* __restrict__ s,
                                         unsigned* __restrict__ part) {
    const int t = threadIdx.x;
    const uint4 gv = ((const uint4*)g)[t];
    const unsigned p01 = gv.x + gv.y;
    const unsigned p012 = p01 + gv.z;
    const unsigned sum = p012 + gv.w;
    part[t] = sum;
    __syncthreads();
    for (int off = 1; off < 256; off <<= 1) {
        unsigned q = (t >= off) ? part[t - off] : 0u;
        __syncthreads();
        part[t] += q;
        __syncthreads();
    }
    const unsigned excl = (t == 0) ? 0u : part[t - 1];
    s[4 * t + 0] = excl + gv.x;
    s[4 * t + 1] = excl + p01;
    s[4 * t + 2] = excl + p012;
    s[4 * t + 3] = excl + sum;
    __syncthreads();
}

// ---------------- Pass A: coarse histogram (LDS, then global atomics) -------
__global__ __launch_bounds__(256, 8) void k_hist(const float* __restrict__ x,
                                                 unsigned* __restrict__ hist) {
    __shared__ unsigned lh[1024];
    const int t = threadIdx.x;
    for (int i = t; i < 1024; i += 256) lh[i] = 0u;
    __syncthreads();

    const int ch = (int)blockIdx.x / BPC;
    const int sub = (int)blockIdx.x % BPC;
    // channel-stride mapping: iteration i covers channel float4s
    // [i*8192, i*8192+8192); this block owns lane-window sub*256+t of it.
    const f32x4* __restrict__ xc =
        (const f32x4*)x + (long long)ch * F4_PER_CH + sub * 256 + t;

    for (int i = 0; i < NIT; i += UNROLL) {
        f32x4 v[UNROLL];
#pragma unroll
        for (int u = 0; u < UNROLL; ++u) v[u] = xc[(i + u) * STRIDE_F4];
#pragma unroll
        for (int u = 0; u < UNROLL; ++u) {
#pragma unroll
            for (int k = 0; k < 4; ++k) {
                const float f = v[u][k];
                if (f > 1e-4f) {
                    int j = (int)(f * 1048576.0f);
                    j = min(j, 1048575);
                    atomicAdd(&lh[j >> 10], 1u);
                }
            }
        }
    }
    __syncthreads();
    unsigned* __restrict__ gh = hist + ch * 1024;
    for (int i = t; i < 1024; i += 256) {
        const unsigned c = lh[i];
        if (c) atomicAdd(&gh[i], c);
    }
}

// ---------------- Pass B: coarse select + fine sub-histograms ---------------
__global__ __launch_bounds__(256, 8) void k_refine(const float* __restrict__ x,
                                                   const unsigned* __restrict__ hist,
                                                   unsigned* __restrict__ sub2,
                                                   unsigned* __restrict__ sub98,
                                                   int* __restrict__ info) {
    __shared__ unsigned s[1024];
    __shared__ unsigned part[256];
    __shared__ int sb2, sr2, sb98, sr98;
    const int t = threadIdx.x;
    const int ch = (int)blockIdx.x / BPC;
    const int sub = (int)blockIdx.x % BPC;
    if (t == 0) { sb2 = -2; sr2 = 0; sb98 = -2; sr98 = 0; }  // ordered by scan's barriers

    scan1024(hist + ch * 1024, s, part);
    const int n = (int)s[1023];  // block-uniform
    if (n > 0) {
        // reference: k = min(p*n//100 + 1, n); idx = k-1 -> min(p*n/100, n-1)
        const int i2 = min((2 * n) / 100, n - 1);
        const int i98 = min((98 * n) / 100, n - 1);  // 98n < 2^31, fits int32
#pragma unroll
        for (int q = 0; q < 4; ++q) {
            const int b = 4 * t + q;
            const unsigned excl = (b == 0) ? 0u : s[b - 1];
            const unsigned incl = s[b];
            if (excl <= (unsigned)i2 && (unsigned)i2 < incl) { sb2 = b; sr2 = i2 - (int)excl; }
            if (excl <= (unsigned)i98 && (unsigned)i98 < incl) { sb98 = b; sr98 = i98 - (int)excl; }
        }
    }
    __syncthreads();
    const int b2 = sb2, b98 = sb98;

    // one block per channel publishes selection state for k_apply (all blocks
    // of a channel compute identical values from the same hist)
    if (sub == 0 && t == 0) {
        info[ch * 8 + 0] = n;
        info[ch * 8 + 1] = b2;
        info[ch * 8 + 2] = sr2;
        info[ch * 8 + 3] = b98;
        info[ch * 8 + 4] = sr98;
    }

    if (n > 0) {
        const f32x4* __restrict__ xc =
            (const f32x4*)x + (long long)ch * F4_PER_CH + sub * 256 + t;
        unsigned* __restrict__ g2 = sub2 + ch * 1024;
        unsigned* __restrict__ g98 = sub98 + ch * 1024;
        for (int i = 0; i < NIT; i += UNROLL) {
            f32x4 v[UNROLL];
#pragma unroll
            for (int u = 0; u < UNROLL; ++u) v[u] = xc[(i + u) * STRIDE_F4];
#pragma unroll
            for (int u = 0; u < UNROLL; ++u) {
#pragma unroll
                for (int k = 0; k < 4; ++k) {
                    const float f = v[u][k];
                    if (f > 1e-4f) {
                        int j = (int)(f * 1048576.0f);  // identical expr to pass A
                        j = min(j, 1048575);
                        const int cb = j >> 10, fb = j & 1023;
                        // ~16 hits/block/bin -> direct global atomics are cheap
                        if (cb == b2) atomicAdd(&g2[fb], 1u);
                        if (cb == b98) atomicAdd(&g98[fb], 1u);
                    }
                }
            }
        }
    }
}

// ---------------- Pass C: fine select + apply -------------------------------
__device__ __forceinline__ float apply_one(float xx, float mn, float isc,
                                           float mean, float istd) {
    float y = (xx - mn) * isc;
    y = fminf(fmaxf(y, 0.0f), 1.0f);
    // y^(1/2.2) via hw log2/exp2; exactly 0 at y==0 like the reference
    const float g = 0.45454547f;
    float p = (y > 0.0f) ? exp2f(g * log2f(y)) : 0.0f;
    return (p - mean) * istd;
}

__global__ __launch_bounds__(256, 8) void k_apply(const float* __restrict__ x,
                                                  float* __restrict__ out,
                                                  const unsigned* __restrict__ sub2,
                                                  const unsigned* __restrict__ sub98,
                                                  const int* __restrict__ info) {
    __shared__ unsigned s[1024];
    __shared__ unsigned part[256];
    __shared__ int sf2, sf98;
    const int t = threadIdx.x;
    const int ch = (int)blockIdx.x / BPC;
    const int sub = (int)blockIdx.x % BPC;

    const int n = info[ch * 8 + 0];
    const int b2 = info[ch * 8 + 1], r2 = info[ch * 8 + 2];
    const int b98 = info[ch * 8 + 3], r98 = info[ch * 8 + 4];
    if (t == 0) { sf2 = 0; sf98 = 0; }  // ordered by scan's barriers

    if (n > 0) {
        scan1024(sub2 + ch * 1024, s, part);
#pragma unroll
        for (int q = 0; q < 4; ++q) {
            const int b = 4 * t + q;
            const unsigned excl = (b == 0) ? 0u : s[b - 1];
            const unsigned incl = s[b];
            if (excl <= (unsigned)r2 && (unsigned)r2 < incl) sf2 = b;
        }
        scan1024(sub98 + ch * 1024, s, part);  // barrier discipline protects s
#pragma unroll
        for (int q = 0; q < 4; ++q) {
            const int b = 4 * t + q;
            const unsigned excl = (b == 0) ? 0u : s[b - 1];
            const unsigned incl = s[b];
            if (excl <= (unsigned)r98 && (unsigned)r98 < incl) sf98 = b;
        }
    }
    __syncthreads();

    const bool use = n > 100;
    float mn, isc;
    if (use) {
        const float v2 = ((float)(b2 * 1024 + sf2) + 0.5f) * (1.0f / 1048576.0f);
        const float v98 = ((float)(b98 * 1024 + sf98) + 0.5f) * (1.0f / 1048576.0f);
        mn = v2;
        isc = 1.0f / fmaxf(v98 - v2, 1e-6f);
    } else {
        mn = 0.0f;
        isc = 1.0f;  // 1/max(1-0, 1e-6)
    }
    const int c3 = ch % 3;
    // explicit selects, not a runtime-indexed array (avoid scratch)
    const float mean = (c3 == 0) ? 0.485f : (c3 == 1) ? 0.456f : 0.406f;
    const float istd = (c3 == 0) ? (1.0f / 0.229f)
                      : (c3 == 1) ? (1.0f / 0.224f) : (1.0f / 0.225f);

    const long long off = (long long)ch * F4_PER_CH + sub * 256 + t;
    const f32x4* __restrict__ xc = (const f32x4*)x + off;
    f32x4* __restrict__ oc = (f32x4*)out + off;

    for (int i = 0; i < NIT; i += UNROLL) {
        f32x4 v[UNROLL];
#pragma unroll
        for (int u = 0; u < UNROLL; ++u)
            v[u] = __builtin_nontemporal_load(&xc[(i + u) * STRIDE_F4]);
#pragma unroll
        for (int u = 0; u < UNROLL; ++u) {
            f32x4 r;
            r.x = apply_one(v[u].x, mn, isc, mean, istd);
            r.y = apply_one(v[u].y, mn, isc, mean, istd);
            r.z = apply_one(v[u].z, mn, isc, mean, istd);
            r.w = apply_one(v[u].w, mn, isc, mean, istd);
            __builtin_nontemporal_store(r, &oc[(i + u) * STRIDE_F4]);
        }
    }
}

extern "C" void kernel_launch(void* const* d_in, const int* in_sizes, int n_in,
                              void* d_out, int out_size, void* d_ws, size_t ws_size,
                              hipStream_t stream) {
    const float* x = (const float*)d_in[0];
    float* out = (float*)d_out;

    // workspace: hist 48*1024 u32 | sub2 48*1024 u32 | sub98 48*1024 u32
    //          | info 48*8 int {n, b2, r2, b98, r98, -, -, -}
    unsigned* hist = (unsigned*)d_ws;
    unsigned* sub2 = hist + NCH * 1024;
    unsigned* sub98 = sub2 + NCH * 1024;
    int* info = (int*)(sub98 + NCH * 1024);
    const size_t ws_zero = (size_t)(3 * NCH * 1024) * 4;  // info fully overwritten

    hipMemsetAsync(d_ws, 0, ws_zero, stream);
    k_hist<<<GRID_STREAM, 256, 0, stream>>>(x, hist);
    k_refine<<<GRID_STREAM, 256, 0, stream>>>(x, hist, sub2, sub98, info);
    k_apply<<<GRID_STREAM, 256, 0, stream>>>(x, out, sub2, sub98, info);
}